// Round 1
// baseline (2142.988 us; speedup 1.0000x reference)
//
#include <hip/hip_runtime.h>

#define NPN   1024            // nodes per slice
#define NB    512             // batch (slices)
#define NE_S  2048            // edges per slice
#define DD    128             // feature dim
#define NN    (NB * NPN)      // 524288 total nodes
#define NE    (NB * NE_S)     // 1048576 total edges

// ---------- CSR / degree precompute (layer-invariant) ----------

__global__ void k_count(const int* __restrict__ ei, int* __restrict__ deg) {
    int t = blockIdx.x * 256 + threadIdx.x;          // 0..NE-1
    int b = t >> 11, e = t & (NE_S - 1);
    int col = ei[b * (2 * NE_S) + NE_S + e];
    atomicAdd(&deg[b * NPN + col], 1);
}

__global__ void k_dinv(const int* __restrict__ deg, float* __restrict__ dinv) {
    int i = blockIdx.x * 256 + threadIdx.x;
    dinv[i] = rsqrtf((float)(deg[i] + 1));           // +1 self-loop
}

__global__ __launch_bounds__(1024) void k_scan(const int* __restrict__ deg,
                                               int* __restrict__ coff,
                                               int* __restrict__ cur) {
    __shared__ int s[NPN];
    int b = blockIdx.x, t = threadIdx.x;
    int v = deg[b * NPN + t];
    s[t] = v;
    __syncthreads();
    for (int off = 1; off < NPN; off <<= 1) {
        int add = (t >= off) ? s[t - off] : 0;
        __syncthreads();
        s[t] += add;
        __syncthreads();
    }
    coff[b * NPN + t] = b * NE_S + (s[t] - v);       // exclusive prefix, global offset
    cur[b * NPN + t] = 0;
}

__global__ void k_fill(const int* __restrict__ ei, const float* __restrict__ dinv,
                       const int* __restrict__ coff, int* __restrict__ cur,
                       int* __restrict__ crow, float* __restrict__ cnorm) {
    int t = blockIdx.x * 256 + threadIdx.x;
    int b = t >> 11, e = t & (NE_S - 1);
    int r = ei[b * (2 * NE_S) + e];
    int c = ei[b * (2 * NE_S) + NE_S + e];
    int gr = b * NPN + r, gc = b * NPN + c;
    int pos = coff[gc] + atomicAdd(&cur[gc], 1);
    crow[pos]  = gr;
    cnorm[pos] = dinv[gr] * dinv[gc];
}

// ---------- layer 1: H = emb @ W1 (shared across slices), then gather ----------

__global__ __launch_bounds__(128) void k_h1(const float* __restrict__ emb,
                                            const float* __restrict__ W,
                                            float* __restrict__ H) {
    __shared__ float se[DD];
    int m = blockIdx.x, t = threadIdx.x;             // 1024 blocks x 128 threads
    se[t] = emb[m * DD + t];
    __syncthreads();
    float acc = 0.f;
    for (int k = 0; k < DD; ++k) acc += se[k] * W[k * DD + t];
    H[m * DD + t] = acc;
}

__global__ __launch_bounds__(256) void k_agg1(const float* __restrict__ H,
                                              const float* __restrict__ bias,
                                              const float* __restrict__ dinv,
                                              const int* __restrict__ coff,
                                              const int* __restrict__ deg,
                                              const int* __restrict__ crow,
                                              const float* __restrict__ cnorm,
                                              float* __restrict__ out) {
    int wave = threadIdx.x >> 6, lane = threadIdx.x & 63;
    int g = blockIdx.x * 4 + wave;
    float dv = dinv[g];
    float2 acc = *(const float2*)&H[(g & (NPN - 1)) * DD + lane * 2];
    acc.x *= dv * dv; acc.y *= dv * dv;
    int beg = coff[g], cnt = deg[g];
    for (int e = 0; e < cnt; ++e) {
        int r = crow[beg + e];
        float nw = cnorm[beg + e];
        float2 hv = *(const float2*)&H[(r & (NPN - 1)) * DD + lane * 2];
        acc.x += nw * hv.x; acc.y += nw * hv.y;
    }
    float2 bv = *(const float2*)&bias[lane * 2];
    float2 o;
    o.x = fmaxf(acc.x + bv.x, 0.f);
    o.y = fmaxf(acc.y + bv.y, 0.f);
    *(float2*)&out[g * DD + lane * 2] = o;
}

// ---------- fused layer (L2/L3): out = relu((A_hat x) @ W + b) ----------
// Per block: 128 output rows. Phase 1: gather y = A_hat x rows into LDS
// (XOR-swizzled on 16B granules -> conflict-free writes AND float4 reads).
// Phase 2: 128x128 @ 128x128 fp32 GEMM, 8x8 micro-tile per thread.

__global__ __launch_bounds__(256) void k_layer(const float* __restrict__ x,
                                               const float* __restrict__ W,
                                               const float* __restrict__ bias,
                                               const float* __restrict__ dinv,
                                               const int* __restrict__ coff,
                                               const int* __restrict__ deg,
                                               const int* __restrict__ crow,
                                               const float* __restrict__ cnorm,
                                               float* __restrict__ out) {
    __shared__ float sW[DD * DD];        // 64 KiB
    __shared__ float sY[128 * DD];       // 64 KiB, granule-swizzled

    int t = threadIdx.x;
    // XCD-aware swizzle: 4096 blocks = 8 XCDs x 512 -> consecutive rows (same
    // slice) share an XCD's L2 for the gather reads.
    int wb = (blockIdx.x & 7) * 512 + (blockIdx.x >> 3);
    int m0 = wb * 128;

    // load W (16384 floats, coalesced float4)
    #pragma unroll
    for (int i = 0; i < 16; ++i) {
        int idx = t * 4 + i * 1024;
        *(float4*)&sW[idx] = *(const float4*)&W[idx];
    }

    // gather phase: wave per row, lane covers 2 features
    int wave = t >> 6, lane = t & 63;
    for (int i = wave; i < 128; i += 4) {
        int g = m0 + i;
        float dv = dinv[g];
        float2 xv = *(const float2*)&x[g * DD + lane * 2];
        float ax = dv * dv * xv.x, ay = dv * dv * xv.y;
        int beg = coff[g], cnt = deg[g];
        for (int e = 0; e < cnt; ++e) {
            int r = crow[beg + e];
            float nw = cnorm[beg + e];
            float2 rv = *(const float2*)&x[r * DD + lane * 2];
            ax += nw * rv.x; ay += nw * rv.y;
        }
        // swizzled store: granule (k>>2) XOR'd with (row&7)
        int gsw = (lane >> 1) ^ (i & 7);             // k = 2*lane
        int pos = i * DD + (gsw << 2) + ((2 * lane) & 3);
        sY[pos]     = ax;
        sY[pos + 1] = ay;
    }
    __syncthreads();

    // GEMM phase
    int tx = t & 15, ty = t >> 4;
    int r0 = 4 * ty, r1 = 64 + 4 * ty;               // 8 rows (granule-split)
    int c0 = 4 * tx, c1 = 64 + 4 * tx;               // 8 cols (granule-split)
    float acc[8][8];
    #pragma unroll
    for (int i = 0; i < 8; ++i)
        #pragma unroll
        for (int j = 0; j < 8; ++j) acc[i][j] = 0.f;

    for (int k = 0; k < DD; k += 4) {
        int g0 = k >> 2;
        float4 a[8];
        #pragma unroll
        for (int i = 0; i < 4; ++i) {
            int ra = r0 + i, rb = r1 + i;
            a[i]     = *(float4*)&sY[ra * DD + (((g0 ^ (ra & 7))) << 2)];
            a[4 + i] = *(float4*)&sY[rb * DD + (((g0 ^ (rb & 7))) << 2)];
        }
        #pragma unroll
        for (int dk = 0; dk < 4; ++dk) {
            float4 b0 = *(float4*)&sW[(k + dk) * DD + c0];
            float4 b1 = *(float4*)&sW[(k + dk) * DD + c1];
            #pragma unroll
            for (int i = 0; i < 8; ++i) {
                float av = (dk == 0) ? a[i].x : (dk == 1) ? a[i].y
                         : (dk == 2) ? a[i].z : a[i].w;
                acc[i][0] += av * b0.x; acc[i][1] += av * b0.y;
                acc[i][2] += av * b0.z; acc[i][3] += av * b0.w;
                acc[i][4] += av * b1.x; acc[i][5] += av * b1.y;
                acc[i][6] += av * b1.z; acc[i][7] += av * b1.w;
            }
        }
    }

    float4 bb0 = *(const float4*)&bias[c0];
    float4 bb1 = *(const float4*)&bias[c1];
    #pragma unroll
    for (int i = 0; i < 8; ++i) {
        int row = (i < 4) ? (r0 + i) : (r1 + i - 4);
        int g = m0 + row;
        float4 v0, v1;
        v0.x = fmaxf(acc[i][0] + bb0.x, 0.f);
        v0.y = fmaxf(acc[i][1] + bb0.y, 0.f);
        v0.z = fmaxf(acc[i][2] + bb0.z, 0.f);
        v0.w = fmaxf(acc[i][3] + bb0.w, 0.f);
        v1.x = fmaxf(acc[i][4] + bb1.x, 0.f);
        v1.y = fmaxf(acc[i][5] + bb1.y, 0.f);
        v1.z = fmaxf(acc[i][6] + bb1.z, 0.f);
        v1.w = fmaxf(acc[i][7] + bb1.w, 0.f);
        *(float4*)&out[g * DD + c0] = v0;
        *(float4*)&out[g * DD + c1] = v1;
    }
}

// ---------- launch ----------

extern "C" void kernel_launch(void* const* d_in, const int* in_sizes, int n_in,
                              void* d_out, int out_size, void* d_ws, size_t ws_size,
                              hipStream_t stream) {
    const int*   ei  = (const int*)d_in[0];
    const float* emb = (const float*)d_in[1];
    const float* W1  = (const float*)d_in[2];
    const float* b1  = (const float*)d_in[3];
    const float* W2  = (const float*)d_in[4];
    const float* b2  = (const float*)d_in[5];
    const float* W3  = (const float*)d_in[6];
    const float* b3  = (const float*)d_in[7];
    float* out = (float*)d_out;

    float* x_mid = (float*)d_ws;                       // NN*DD floats (256 MiB)
    float* dinv  = x_mid + (size_t)NN * DD;
    int*   deg   = (int*)(dinv + NN);
    int*   coff  = deg + NN;
    int*   cur   = coff + NN;
    int*   crow  = cur + NN;
    float* cnorm = (float*)(crow + NE);
    float* H     = cnorm + NE;                         // NPN*DD floats

    hipMemsetAsync(deg, 0, NN * sizeof(int), stream);
    k_count<<<NE / 256, 256, 0, stream>>>(ei, deg);
    k_dinv<<<NN / 256, 256, 0, stream>>>(deg, dinv);
    k_scan<<<NB, NPN, 0, stream>>>(deg, coff, cur);
    k_fill<<<NE / 256, 256, 0, stream>>>(ei, dinv, coff, cur, crow, cnorm);

    // layer 1: shared tiny GEMM + gather  -> x1 in d_out
    k_h1<<<NPN, DD, 0, stream>>>(emb, W1, H);
    k_agg1<<<NN / 4, 256, 0, stream>>>(H, b1, dinv, coff, deg, crow, cnorm, out);

    // layer 2: x1(d_out) -> x2(ws)
    k_layer<<<NN / 128, 256, 0, stream>>>(out, W2, b2, dinv, coff, deg, crow, cnorm, x_mid);
    // layer 3: x2(ws) -> d_out
    k_layer<<<NN / 128, 256, 0, stream>>>(x_mid, W3, b3, dinv, coff, deg, crow, cnorm, out);
}

// Round 2
// 1095.031 us; speedup vs baseline: 1.9570x; 1.9570x over previous
//
#include <hip/hip_runtime.h>

#define NPN   1024            // nodes per slice
#define NB    512             // batch (slices)
#define NE_S  2048            // edges per slice
#define DD    128             // feature dim
#define NN    (NB * NPN)      // 524288 total nodes
#define NE    (NB * NE_S)     // 1048576 total edges

typedef short s16x8 __attribute__((ext_vector_type(8)));
typedef float f32x4 __attribute__((ext_vector_type(4)));

static __device__ __forceinline__ unsigned short f2bf(float f) {
    unsigned u = __builtin_bit_cast(unsigned, f);
    unsigned r = (u + 0x7FFFu + ((u >> 16) & 1u)) >> 16;   // RNE
    return (unsigned short)r;
}
static __device__ __forceinline__ float bf2f(unsigned short h) {
    unsigned u = ((unsigned)h) << 16;
    return __builtin_bit_cast(float, u);
}

// ---------- CSR / degree precompute (layer-invariant) ----------

__global__ void k_count(const int* __restrict__ ei, int* __restrict__ deg) {
    int t = blockIdx.x * 256 + threadIdx.x;          // 0..NE-1
    int b = t >> 11, e = t & (NE_S - 1);
    int col = ei[b * (2 * NE_S) + NE_S + e];
    atomicAdd(&deg[b * NPN + col], 1);
}

__global__ void k_dinv(const int* __restrict__ deg, float* __restrict__ dinv) {
    int i = blockIdx.x * 256 + threadIdx.x;
    dinv[i] = rsqrtf((float)(deg[i] + 1));           // +1 self-loop
}

__global__ __launch_bounds__(1024) void k_scan(const int* __restrict__ deg,
                                               int* __restrict__ coff,
                                               int* __restrict__ cur) {
    __shared__ int s[NPN];
    int b = blockIdx.x, t = threadIdx.x;
    int v = deg[b * NPN + t];
    s[t] = v;
    __syncthreads();
    for (int off = 1; off < NPN; off <<= 1) {
        int add = (t >= off) ? s[t - off] : 0;
        __syncthreads();
        s[t] += add;
        __syncthreads();
    }
    coff[b * NPN + t] = b * NE_S + (s[t] - v);       // exclusive prefix, global offset
    cur[b * NPN + t] = 0;
}

__global__ void k_fill(const int* __restrict__ ei, const float* __restrict__ dinv,
                       const int* __restrict__ coff, int* __restrict__ cur,
                       int* __restrict__ crow, float* __restrict__ cnorm) {
    int t = blockIdx.x * 256 + threadIdx.x;
    int b = t >> 11, e = t & (NE_S - 1);
    int r = ei[b * (2 * NE_S) + e];
    int c = ei[b * (2 * NE_S) + NE_S + e];
    int gr = b * NPN + r, gc = b * NPN + c;
    int pos = coff[gc] + atomicAdd(&cur[gc], 1);
    crow[pos]  = gr;
    cnorm[pos] = dinv[gr] * dinv[gc];
}

// ---------- W pre-transpose + bf16 hi/lo split (per layer, tiny) ----------
// W[k][n] f32  ->  WTh[n][k], WTl[n][k] bf16

__global__ __launch_bounds__(256) void k_wsplit(const float* __restrict__ W,
                                                short* __restrict__ WTh,
                                                short* __restrict__ WTl) {
    int idx = blockIdx.x * 256 + threadIdx.x;        // 0..16383
    int k = idx >> 7, n = idx & 127;
    float f = W[idx];
    unsigned short h = f2bf(f);
    unsigned short l = f2bf(f - bf2f(h));
    WTh[n * DD + k] = (short)h;
    WTl[n * DD + k] = (short)l;
}

// ---------- fused GCN layer: out = relu((A_hat x) @ W + b) ----------
// 512 thr / 8 waves per block, 128x128 output tile.
// Phase 1 (gather): wave w computes rows w*16..w*16+15 of y = A_hat x,
//   splits to bf16 hi/lo, stores XOR-swizzled into LDS.
// Phase 2 (MFMA): wave w owns the 128x16 output strip at cols w*16..+15;
//   B-fragments (pre-transposed, hi/lo split W) live in 32 VGPRs, loaded
//   once from L2. 4 MFMAs per (kstep,m): hh + hl + lh + ll ~ fp32 accuracy.
// gmask: layer 1 passes 1023 so x-row indices fold onto the shared
//   embedding table (A_hat(x)W == (A_hat x)W and x is tiled emb).

__global__ __launch_bounds__(512, 4) void k_layer(const float* __restrict__ x,
                                                  unsigned gmask,
                                                  const short* __restrict__ WTh,
                                                  const short* __restrict__ WTl,
                                                  const float* __restrict__ bias,
                                                  const float* __restrict__ dinv,
                                                  const int* __restrict__ coff,
                                                  const int* __restrict__ deg,
                                                  const int* __restrict__ crow,
                                                  const float* __restrict__ cnorm,
                                                  float* __restrict__ out) {
    __shared__ short sH[128 * DD];       // A_hi, 32 KiB, swizzled
    __shared__ short sL[128 * DD];       // A_lo, 32 KiB, swizzled

    int t = threadIdx.x;
    int wave = t >> 6, lane = t & 63;
    // XCD-aware swizzle: 8 blocks/slice land on one XCD -> slice rows L2-hit
    int wb = (int)((blockIdx.x & 7) * 512 + (blockIdx.x >> 3));
    int m0 = wb * 128;

    int n  = lane & 15;                  // fragment row/col within 16
    int kq = lane >> 4;                  // k-quad (8 bf16 each)

    // ---- B fragments from global (L2-resident 64 KB, loaded once) ----
    const short* bhp = &WTh[(wave * 16 + n) * DD + kq * 8];
    const short* blp = &WTl[(wave * 16 + n) * DD + kq * 8];
    s16x8 bh[4], bl[4];
    #pragma unroll
    for (int ks = 0; ks < 4; ++ks) {
        bh[ks] = *(const s16x8*)(bhp + ks * 32);
        bl[ks] = *(const s16x8*)(blp + ks * 32);
    }

    // ---- gather phase ----
    for (int i = 0; i < 16; ++i) {
        int row = wave * 16 + i;
        int g = m0 + row;
        float dv = dinv[g];
        float2 v = *(const float2*)&x[(size_t)(g & gmask) * DD + lane * 2];
        float ax = dv * dv * v.x, ay = dv * dv * v.y;
        int beg = coff[g], cnt = deg[g];
        for (int e = 0; e < cnt; ++e) {
            int r = crow[beg + e];
            float nw = cnorm[beg + e];
            float2 rv = *(const float2*)&x[(size_t)(r & gmask) * DD + lane * 2];
            ax += nw * rv.x; ay += nw * rv.y;
        }
        unsigned short hx = f2bf(ax); unsigned short lx = f2bf(ax - bf2f(hx));
        unsigned short hy = f2bf(ay); unsigned short ly = f2bf(ay - bf2f(hy));
        unsigned hwrd = ((unsigned)hy << 16) | hx;
        unsigned lwrd = ((unsigned)ly << 16) | lx;
        unsigned bo = ((unsigned)row * 256u + (unsigned)lane * 4u) ^ ((unsigned)(row & 7) << 4);
        *(unsigned*)((char*)sH + bo) = hwrd;
        *(unsigned*)((char*)sL + bo) = lwrd;
    }
    __syncthreads();

    // ---- MFMA phase: wave strip = rows 0..127, cols wave*16..+15 ----
    f32x4 acc[8];
    #pragma unroll
    for (int m = 0; m < 8; ++m) acc[m] = (f32x4){0.f, 0.f, 0.f, 0.f};

    #pragma unroll
    for (int ks = 0; ks < 4; ++ks) {
        #pragma unroll
        for (int m = 0; m < 8; ++m) {
            int row = m * 16 + n;
            unsigned bo = ((unsigned)row * 256u + (unsigned)(ks * 64 + kq * 16))
                          ^ ((unsigned)(row & 7) << 4);
            s16x8 ah = *(const s16x8*)((const char*)sH + bo);
            s16x8 al = *(const s16x8*)((const char*)sL + bo);
            acc[m] = __builtin_amdgcn_mfma_f32_16x16x32_bf16(ah, bh[ks], acc[m], 0, 0, 0);
            acc[m] = __builtin_amdgcn_mfma_f32_16x16x32_bf16(ah, bl[ks], acc[m], 0, 0, 0);
            acc[m] = __builtin_amdgcn_mfma_f32_16x16x32_bf16(al, bh[ks], acc[m], 0, 0, 0);
            acc[m] = __builtin_amdgcn_mfma_f32_16x16x32_bf16(al, bl[ks], acc[m], 0, 0, 0);
        }
    }

    // ---- epilogue: bias + relu, C/D layout col=lane&15, row=kq*4+reg ----
    int col = wave * 16 + n;
    float bv = bias[col];
    #pragma unroll
    for (int m = 0; m < 8; ++m) {
        #pragma unroll
        for (int r = 0; r < 4; ++r) {
            int row = m * 16 + kq * 4 + r;
            float vv = acc[m][r] + bv;
            out[(size_t)(m0 + row) * DD + col] = fmaxf(vv, 0.f);
        }
    }
}

// ---------- launch ----------

extern "C" void kernel_launch(void* const* d_in, const int* in_sizes, int n_in,
                              void* d_out, int out_size, void* d_ws, size_t ws_size,
                              hipStream_t stream) {
    const int*   ei  = (const int*)d_in[0];
    const float* emb = (const float*)d_in[1];
    const float* W1  = (const float*)d_in[2];
    const float* b1  = (const float*)d_in[3];
    const float* W2  = (const float*)d_in[4];
    const float* b2  = (const float*)d_in[5];
    const float* W3  = (const float*)d_in[6];
    const float* b3  = (const float*)d_in[7];
    float* out = (float*)d_out;

    float* x_mid = (float*)d_ws;                       // NN*DD floats (256 MiB)
    float* dinv  = x_mid + (size_t)NN * DD;
    int*   deg   = (int*)(dinv + NN);
    int*   coff  = deg + NN;
    int*   cur   = coff + NN;
    int*   crow  = cur + NN;
    float* cnorm = (float*)(crow + NE);
    short* WTh1  = (short*)(cnorm + NE);
    short* WTl1  = WTh1 + DD * DD;
    short* WTh2  = WTl1 + DD * DD;
    short* WTl2  = WTh2 + DD * DD;
    short* WTh3  = WTl2 + DD * DD;
    short* WTl3  = WTh3 + DD * DD;

    hipMemsetAsync(deg, 0, NN * sizeof(int), stream);
    k_count<<<NE / 256, 256, 0, stream>>>(ei, deg);
    k_dinv<<<NN / 256, 256, 0, stream>>>(deg, dinv);
    k_scan<<<NB, NPN, 0, stream>>>(deg, coff, cur);
    k_fill<<<NE / 256, 256, 0, stream>>>(ei, dinv, coff, cur, crow, cnorm);

    k_wsplit<<<64, 256, 0, stream>>>(W1, WTh1, WTl1);
    k_wsplit<<<64, 256, 0, stream>>>(W2, WTh2, WTl2);
    k_wsplit<<<64, 256, 0, stream>>>(W3, WTh3, WTl3);

    // layer 1: x = tiled emb (gmask folds node id onto the 1024-row table)
    k_layer<<<NN / 128, 512, 0, stream>>>(emb, NPN - 1, WTh1, WTl1, b1,
                                          dinv, coff, deg, crow, cnorm, out);
    // layer 2: out -> x_mid
    k_layer<<<NN / 128, 512, 0, stream>>>(out, 0xFFFFFFFFu, WTh2, WTl2, b2,
                                          dinv, coff, deg, crow, cnorm, x_mid);
    // layer 3: x_mid -> out
    k_layer<<<NN / 128, 512, 0, stream>>>(x_mid, 0xFFFFFFFFu, WTh3, WTl3, b3,
                                          dinv, coff, deg, crow, cnorm, out);
}